// Round 1
// baseline (625.626 us; speedup 1.0000x reference)
//
#include <hip/hip_runtime.h>

#define NEG_ATT 0.2f

// ---------------- CSR build ----------------

__global__ __launch_bounds__(256) void init_cnt_k(int* cnt, int N) {
    int i = blockIdx.x * 256 + threadIdx.x;
    if (i < N) cnt[i] = 1;  // self-loop
}

__global__ __launch_bounds__(256) void count_k(const int* __restrict__ dst, int* cnt, int E) {
    int i = blockIdx.x * 256 + threadIdx.x;
    if (i < E) atomicAdd(&cnt[dst[i]], 1);
}

__global__ __launch_bounds__(256) void scan_block_k(const int* __restrict__ cnt, int* rowp, int* bsum, int N) {
    __shared__ int s[256];
    int t = threadIdx.x;
    int i = blockIdx.x * 256 + t;
    s[t] = (i < N) ? cnt[i] : 0;
    __syncthreads();
    #pragma unroll
    for (int off = 1; off < 256; off <<= 1) {
        int v = (t >= off) ? s[t - off] : 0;
        __syncthreads();
        s[t] += v;
        __syncthreads();
    }
    if (i < N) rowp[i + 1] = s[t];
    if (t == 255) bsum[blockIdx.x] = s[255];
}

__global__ void scan_bsum_k(int* bsum, int nb) {
    __shared__ int s[256];
    int t = threadIdx.x;
    s[t] = (t < nb) ? bsum[t] : 0;
    __syncthreads();
    if (t == 0) {
        int run = 0;
        for (int i = 0; i < nb; i++) { int v = s[i]; s[i] = run; run += v; }
    }
    __syncthreads();
    if (t < nb) bsum[t] = s[t];
}

__global__ __launch_bounds__(256) void add_off_k(int* rowp, const int* __restrict__ bsum, int* cnt, int N) {
    int i = blockIdx.x * 256 + threadIdx.x;
    if (i < N) { rowp[i + 1] += bsum[blockIdx.x]; cnt[i] = 0; }
    if (i == 0) rowp[0] = 0;
}

__global__ __launch_bounds__(256) void scatter_k(const int* __restrict__ src, const int* __restrict__ dst,
                                                 const int* __restrict__ rowp, int* cnt, int* col,
                                                 int E, int N) {
    int i = blockIdx.x * 256 + threadIdx.x;
    if (i < E) {
        int d = dst[i];
        int p = rowp[d] + atomicAdd(&cnt[d], 1);
        col[p] = src[i];
    } else if (i < E + N) {
        int d = i - E;
        int p = rowp[d] + atomicAdd(&cnt[d], 1);
        col[p] = d;
    }
}

// ---------------- GEMM: H = X @ W  (fp32, W+X in LDS, register tiling) ----------------

template <int CIN, int COUT>
__global__ __launch_bounds__(256) void gemm_k(const float* __restrict__ X, const float* __restrict__ W,
                                              float* __restrict__ H, int N) {
    constexpr int RB  = (CIN == 128 && COUT == 64) ? 32 : 64;  // keep LDS < 64KB
    constexpr int NCT = COUT / 4;       // col-threads (32/16/8)
    constexpr int NRT = 256 / NCT;      // row-threads
    constexpr int RT  = RB / NRT;       // rows per thread
    __shared__ float Xs[RB][CIN];
    __shared__ float Ws[CIN][COUT];
    int tid  = threadIdx.x;
    int row0 = blockIdx.x * RB;

    for (int i = tid; i < CIN * COUT; i += 256) ((float*)Ws)[i] = W[i];
    for (int i = tid; i < RB * CIN; i += 256) {
        int r = i / CIN, k = i % CIN;
        int gr = row0 + r;
        ((float*)Xs)[i] = (gr < N) ? X[gr * CIN + k] : 0.f;
    }
    __syncthreads();

    int ct = tid % NCT;
    int rt = tid / NCT;
    float acc[RT][4] = {};
    #pragma unroll 4
    for (int k = 0; k < CIN; ++k) {
        float w0 = Ws[k][ct];
        float w1 = Ws[k][ct + NCT];
        float w2 = Ws[k][ct + 2 * NCT];
        float w3 = Ws[k][ct + 3 * NCT];
        #pragma unroll
        for (int i = 0; i < RT; ++i) {
            float xv = Xs[rt + i * NRT][k];
            acc[i][0] += xv * w0;
            acc[i][1] += xv * w1;
            acc[i][2] += xv * w2;
            acc[i][3] += xv * w3;
        }
    }
    #pragma unroll
    for (int i = 0; i < RT; ++i) {
        int gr = row0 + rt + i * NRT;
        if (gr < N) {
            #pragma unroll
            for (int j = 0; j < 4; ++j)
                H[gr * COUT + ct + j * NCT] = acc[i][j];
        }
    }
}

// ---------------- attention logits: as = h.a_src, ad = h.a_dst (wave per node) ----------------

template <int COUT>
__global__ __launch_bounds__(256) void att_k(const float* __restrict__ H, const float* __restrict__ a_s,
                                             const float* __restrict__ a_d, float* __restrict__ as_,
                                             float* __restrict__ ad_, int N) {
    int wid  = (blockIdx.x * 256 + threadIdx.x) >> 6;
    int lane = threadIdx.x & 63;
    if (wid >= N) return;
    float s1 = 0.f, s2 = 0.f;
    for (int c = lane; c < COUT; c += 64) {
        float h = H[wid * COUT + c];
        s1 += h * a_s[c];
        s2 += h * a_d[c];
    }
    #pragma unroll
    for (int off = 32; off; off >>= 1) {
        s1 += __shfl_xor(s1, off);
        s2 += __shfl_xor(s2, off);
    }
    if (lane == 0) { as_[wid] = s1; ad_[wid] = s2; }
}

// ---------------- aggregate: out[d] = sum_e softmax(e)*h[src_e] + b, then leaky ----------------

template <int COUT>
__global__ __launch_bounds__(256) void agg_k(const float* __restrict__ H, const float* __restrict__ as_,
                                             const float* __restrict__ ad_, const int* __restrict__ rowp,
                                             const int* __restrict__ col, const float* __restrict__ bias,
                                             float* __restrict__ out, float slope_act, int N) {
    int wid  = (blockIdx.x * 256 + threadIdx.x) >> 6;
    int lane = threadIdx.x & 63;
    if (wid >= N) return;
    constexpr int CPT = (COUT + 63) / 64;
    float adi = ad_[wid];
    int beg = rowp[wid], end = rowp[wid + 1];
    float denom = 0.f;
    float acc[CPT] = {};
    for (int j = beg; j < end; ++j) {
        int s = col[j];
        float e = as_[s] + adi;
        e = e > 0.f ? e : NEG_ATT * e;
        float w = __expf(e);
        denom += w;
        #pragma unroll
        for (int cc = 0; cc < CPT; ++cc) {
            int c = lane + cc * 64;
            if (c < COUT) acc[cc] += w * H[s * COUT + c];
        }
    }
    float inv = 1.f / denom;
    #pragma unroll
    for (int cc = 0; cc < CPT; ++cc) {
        int c = lane + cc * 64;
        if (c < COUT) {
            float v = acc[cc] * inv + bias[c];
            out[wid * COUT + c] = v > 0.f ? v : slope_act * v;
        }
    }
}

// ---------------- launch ----------------

extern "C" void kernel_launch(void* const* d_in, const int* in_sizes, int n_in,
                              void* d_out, int out_size, void* d_ws, size_t ws_size,
                              hipStream_t stream) {
    const float* x  = (const float*)d_in[0];
    const int* ei   = (const int*)d_in[1];
    const float* W1 = (const float*)d_in[2];
    const float* a1s = (const float*)d_in[3];
    const float* a1d = (const float*)d_in[4];
    const float* b1  = (const float*)d_in[5];
    const float* W2 = (const float*)d_in[6];
    const float* a2s = (const float*)d_in[7];
    const float* a2d = (const float*)d_in[8];
    const float* b2  = (const float*)d_in[9];
    const float* W3 = (const float*)d_in[10];
    const float* a3s = (const float*)d_in[11];
    const float* a3d = (const float*)d_in[12];
    const float* b3  = (const float*)d_in[13];
    const float* W4 = (const float*)d_in[14];
    const float* a4s = (const float*)d_in[15];
    const float* a4d = (const float*)d_in[16];
    const float* b4  = (const float*)d_in[17];

    const int N = in_sizes[0] / 64;     // 50000
    const int E = in_sizes[1] / 2;      // 800000
    const int ET = E + N;               // with self-loops
    const int* src = ei;
    const int* dst = ei + E;

    // workspace layout
    float* actA = (float*)d_ws;             // N*128
    float* actB = actA + (size_t)N * 128;   // N*128
    float* as_  = actB + (size_t)N * 128;   // N
    float* ad_  = as_ + N;                  // N
    int* cnt    = (int*)(ad_ + N);          // N
    int* rowp   = cnt + N;                  // N+1
    int* col    = rowp + N + 1;             // ET
    int* bsum   = col + ET;                 // <=256

    const int NB = (N + 255) / 256;         // 196

    // ---- CSR build (dst-sorted), shared across all 4 layers ----
    init_cnt_k<<<NB, 256, 0, stream>>>(cnt, N);
    count_k<<<(E + 255) / 256, 256, 0, stream>>>(dst, cnt, E);
    scan_block_k<<<NB, 256, 0, stream>>>(cnt, rowp, bsum, N);
    scan_bsum_k<<<1, 256, 0, stream>>>(bsum, NB);
    add_off_k<<<NB, 256, 0, stream>>>(rowp, bsum, cnt, N);
    scatter_k<<<(ET + 255) / 256, 256, 0, stream>>>(src, dst, rowp, cnt, col, E, N);

    const int NWAVE = (N * 64 + 255) / 256;  // wave-per-node grids

    // ---- layer 1: 64 -> 128 ----
    gemm_k<64, 128><<<(N + 63) / 64, 256, 0, stream>>>(x, W1, actA, N);
    att_k<128><<<NWAVE, 256, 0, stream>>>(actA, a1s, a1d, as_, ad_, N);
    agg_k<128><<<NWAVE, 256, 0, stream>>>(actA, as_, ad_, rowp, col, b1, actB, 0.01f, N);

    // ---- layer 2: 128 -> 64 ----
    gemm_k<128, 64><<<(N + 31) / 32, 256, 0, stream>>>(actB, W2, actA, N);
    att_k<64><<<NWAVE, 256, 0, stream>>>(actA, a2s, a2d, as_, ad_, N);
    agg_k<64><<<NWAVE, 256, 0, stream>>>(actA, as_, ad_, rowp, col, b2, actB, 0.01f, N);

    // ---- layer 3: 64 -> 128 ----
    gemm_k<64, 128><<<(N + 63) / 64, 256, 0, stream>>>(actB, W3, actA, N);
    att_k<128><<<NWAVE, 256, 0, stream>>>(actA, a3s, a3d, as_, ad_, N);
    agg_k<128><<<NWAVE, 256, 0, stream>>>(actA, as_, ad_, rowp, col, b3, actB, 0.01f, N);

    // ---- layer 4: 128 -> 32 ----
    gemm_k<128, 32><<<(N + 63) / 64, 256, 0, stream>>>(actB, W4, actA, N);
    att_k<32><<<NWAVE, 256, 0, stream>>>(actA, a4s, a4d, as_, ad_, N);
    agg_k<32><<<NWAVE, 256, 0, stream>>>(actA, as_, ad_, rowp, col, b4, (float*)d_out, 1.0f, N);
}

// Round 2
// 412.465 us; speedup vs baseline: 1.5168x; 1.5168x over previous
//
#include <hip/hip_runtime.h>

#define NEG_ATT 0.2f

// ---------------- CSR build ----------------

__global__ __launch_bounds__(256) void init_cnt_k(int* cnt, int N) {
    int i = blockIdx.x * 256 + threadIdx.x;
    if (i < N) cnt[i] = 1;  // self-loop
}

__global__ __launch_bounds__(256) void count_k(const int* __restrict__ dst, int* cnt, int E) {
    int i = blockIdx.x * 256 + threadIdx.x;
    if (i < E) atomicAdd(&cnt[dst[i]], 1);
}

__global__ __launch_bounds__(256) void scan_block_k(const int* __restrict__ cnt, int* rowp, int* bsum, int N) {
    __shared__ int s[256];
    int t = threadIdx.x;
    int i = blockIdx.x * 256 + t;
    s[t] = (i < N) ? cnt[i] : 0;
    __syncthreads();
    #pragma unroll
    for (int off = 1; off < 256; off <<= 1) {
        int v = (t >= off) ? s[t - off] : 0;
        __syncthreads();
        s[t] += v;
        __syncthreads();
    }
    if (i < N) rowp[i + 1] = s[t];
    if (t == 255) bsum[blockIdx.x] = s[255];
}

__global__ void scan_bsum_k(int* bsum, int nb) {
    __shared__ int s[256];
    int t = threadIdx.x;
    s[t] = (t < nb) ? bsum[t] : 0;
    __syncthreads();
    if (t == 0) {
        int run = 0;
        for (int i = 0; i < nb; i++) { int v = s[i]; s[i] = run; run += v; }
    }
    __syncthreads();
    if (t < nb) bsum[t] = s[t];
}

__global__ __launch_bounds__(256) void add_off_k(int* rowp, const int* __restrict__ bsum, int* cnt, int N) {
    int i = blockIdx.x * 256 + threadIdx.x;
    if (i < N) { rowp[i + 1] += bsum[blockIdx.x]; cnt[i] = 0; }
    if (i == 0) rowp[0] = 0;
}

__global__ __launch_bounds__(256) void scatter_k(const int* __restrict__ src, const int* __restrict__ dst,
                                                 const int* __restrict__ rowp, int* cnt, int* col,
                                                 int E, int N) {
    int i = blockIdx.x * 256 + threadIdx.x;
    if (i < E) {
        int d = dst[i];
        int p = rowp[d] + atomicAdd(&cnt[d], 1);
        col[p] = src[i];
    } else if (i < E + N) {
        int d = i - E;
        int p = rowp[d] + atomicAdd(&cnt[d], 1);
        col[p] = d;
    }
}

// ---------------- GEMM + fused attention logits ----------------
// H = X @ W; as_[r] = H[r,:].a_src; ad_[r] = H[r,:].a_dst

template <int CIN, int COUT>
__global__ __launch_bounds__(256) void gemm_att_k(const float* __restrict__ X, const float* __restrict__ W,
                                                  const float* __restrict__ a_s, const float* __restrict__ a_d,
                                                  float* __restrict__ H, float* __restrict__ as_,
                                                  float* __restrict__ ad_, int N) {
    constexpr int RB  = (CIN == 128 && COUT == 64) ? 32 : 64;  // keep LDS at 48KB
    constexpr int NCT = COUT / 4;       // col-threads (32/16/8), contiguous lanes share a row
    constexpr int NRT = 256 / NCT;      // row-threads
    constexpr int RT  = RB / NRT;       // rows per thread
    __shared__ float Xs[RB][CIN];
    __shared__ float Ws[CIN][COUT];
    int tid  = threadIdx.x;
    int row0 = blockIdx.x * RB;

    for (int i = tid; i < CIN * COUT; i += 256) ((float*)Ws)[i] = W[i];
    for (int i = tid; i < RB * CIN; i += 256) {
        int r = i / CIN, k = i % CIN;
        int gr = row0 + r;
        ((float*)Xs)[i] = (gr < N) ? X[gr * CIN + k] : 0.f;
    }
    __syncthreads();

    int ct = tid % NCT;
    int rt = tid / NCT;
    float acc[RT][4] = {};
    #pragma unroll 4
    for (int k = 0; k < CIN; ++k) {
        float w0 = Ws[k][ct];
        float w1 = Ws[k][ct + NCT];
        float w2 = Ws[k][ct + 2 * NCT];
        float w3 = Ws[k][ct + 3 * NCT];
        #pragma unroll
        for (int i = 0; i < RT; ++i) {
            float xv = Xs[rt + i * NRT][k];
            acc[i][0] += xv * w0;
            acc[i][1] += xv * w1;
            acc[i][2] += xv * w2;
            acc[i][3] += xv * w3;
        }
    }

    // attention vectors for this thread's 4 columns
    float asv[4], adv[4];
    #pragma unroll
    for (int j = 0; j < 4; ++j) {
        asv[j] = a_s[ct + j * NCT];
        adv[j] = a_d[ct + j * NCT];
    }

    #pragma unroll
    for (int i = 0; i < RT; ++i) {
        int gr = row0 + rt + i * NRT;
        // row dot products, butterfly over the NCT lanes sharing this row
        float s1 = acc[i][0] * asv[0] + acc[i][1] * asv[1] + acc[i][2] * asv[2] + acc[i][3] * asv[3];
        float s2 = acc[i][0] * adv[0] + acc[i][1] * adv[1] + acc[i][2] * adv[2] + acc[i][3] * adv[3];
        #pragma unroll
        for (int off = 1; off < NCT; off <<= 1) {
            s1 += __shfl_xor(s1, off);
            s2 += __shfl_xor(s2, off);
        }
        if (gr < N) {
            #pragma unroll
            for (int j = 0; j < 4; ++j)
                H[gr * COUT + ct + j * NCT] = acc[i][j];
            if (ct == 0) { as_[gr] = s1; ad_[gr] = s2; }
        }
    }
}

// ---------------- aggregate: out[d] = sum_e softmax(e)*h[src_e] + b, then leaky ----------------
// Wave per node. Phase 1: lanes load up to 64 edges' (col, weight) in parallel.
// Phase 2: broadcast via shuffle, 8 independent H-row gathers in flight.

template <int COUT>
__global__ __launch_bounds__(256) void agg_k(const float* __restrict__ H, const float* __restrict__ as_,
                                             const float* __restrict__ ad_, const int* __restrict__ rowp,
                                             const int* __restrict__ col, const float* __restrict__ bias,
                                             float* __restrict__ out, float slope_act, int N) {
    int wid  = (blockIdx.x * 256 + threadIdx.x) >> 6;
    int lane = threadIdx.x & 63;
    if (wid >= N) return;
    constexpr int CPT = (COUT + 63) / 64;
    float adi = ad_[wid];
    int beg = rowp[wid], end = rowp[wid + 1];
    float denom = 0.f;
    float acc[CPT] = {};

    for (int base = beg; base < end; base += 64) {
        int cnt = end - base;
        if (cnt > 64) cnt = 64;
        int s_l = 0; float w_l = 0.f;
        if (lane < cnt) {
            s_l = col[base + lane];
            float e = as_[s_l] + adi;
            e = e > 0.f ? e : NEG_ATT * e;
            w_l = __expf(e);
        }
        denom += w_l;

        int j = 0;
        for (; j + 8 <= cnt; j += 8) {
            int ss[8]; float ww[8];
            #pragma unroll
            for (int u = 0; u < 8; ++u) {
                ss[u] = __shfl(s_l, j + u);
                ww[u] = __shfl(w_l, j + u);
            }
            #pragma unroll
            for (int cc = 0; cc < CPT; ++cc) {
                int c = lane + cc * 64;
                if (c < COUT) {
                    float hv[8];
                    #pragma unroll
                    for (int u = 0; u < 8; ++u) hv[u] = H[(size_t)ss[u] * COUT + c];
                    float a = acc[cc];
                    #pragma unroll
                    for (int u = 0; u < 8; ++u) a += ww[u] * hv[u];
                    acc[cc] = a;
                }
            }
        }
        for (; j < cnt; ++j) {
            int s = __shfl(s_l, j);
            float w = __shfl(w_l, j);
            #pragma unroll
            for (int cc = 0; cc < CPT; ++cc) {
                int c = lane + cc * 64;
                if (c < COUT) acc[cc] += w * H[(size_t)s * COUT + c];
            }
        }
    }

    // total denom across lanes
    #pragma unroll
    for (int off = 32; off; off >>= 1) denom += __shfl_xor(denom, off);

    float inv = 1.f / denom;
    #pragma unroll
    for (int cc = 0; cc < CPT; ++cc) {
        int c = lane + cc * 64;
        if (c < COUT) {
            float v = acc[cc] * inv + bias[c];
            out[wid * COUT + c] = v > 0.f ? v : slope_act * v;
        }
    }
}

// ---------------- launch ----------------

extern "C" void kernel_launch(void* const* d_in, const int* in_sizes, int n_in,
                              void* d_out, int out_size, void* d_ws, size_t ws_size,
                              hipStream_t stream) {
    const float* x  = (const float*)d_in[0];
    const int* ei   = (const int*)d_in[1];
    const float* W1 = (const float*)d_in[2];
    const float* a1s = (const float*)d_in[3];
    const float* a1d = (const float*)d_in[4];
    const float* b1  = (const float*)d_in[5];
    const float* W2 = (const float*)d_in[6];
    const float* a2s = (const float*)d_in[7];
    const float* a2d = (const float*)d_in[8];
    const float* b2  = (const float*)d_in[9];
    const float* W3 = (const float*)d_in[10];
    const float* a3s = (const float*)d_in[11];
    const float* a3d = (const float*)d_in[12];
    const float* b3  = (const float*)d_in[13];
    const float* W4 = (const float*)d_in[14];
    const float* a4s = (const float*)d_in[15];
    const float* a4d = (const float*)d_in[16];
    const float* b4  = (const float*)d_in[17];

    const int N = in_sizes[0] / 64;     // 50000
    const int E = in_sizes[1] / 2;      // 800000
    const int ET = E + N;               // with self-loops
    const int* src = ei;
    const int* dst = ei + E;

    // workspace layout
    float* actA = (float*)d_ws;             // N*128
    float* actB = actA + (size_t)N * 128;   // N*128
    float* as_  = actB + (size_t)N * 128;   // N
    float* ad_  = as_ + N;                  // N
    int* cnt    = (int*)(ad_ + N);          // N
    int* rowp   = cnt + N;                  // N+1
    int* col    = rowp + N + 1;             // ET
    int* bsum   = col + ET;                 // <=256

    const int NB = (N + 255) / 256;         // 196

    // ---- CSR build (dst-sorted), shared across all 4 layers ----
    init_cnt_k<<<NB, 256, 0, stream>>>(cnt, N);
    count_k<<<(E + 255) / 256, 256, 0, stream>>>(dst, cnt, E);
    scan_block_k<<<NB, 256, 0, stream>>>(cnt, rowp, bsum, N);
    scan_bsum_k<<<1, 256, 0, stream>>>(bsum, NB);
    add_off_k<<<NB, 256, 0, stream>>>(rowp, bsum, cnt, N);
    scatter_k<<<(ET + 255) / 256, 256, 0, stream>>>(src, dst, rowp, cnt, col, E, N);

    const int NWAVE = (N * 64 + 255) / 256;  // wave-per-node grids

    // ---- layer 1: 64 -> 128 ----
    gemm_att_k<64, 128><<<(N + 63) / 64, 256, 0, stream>>>(x, W1, a1s, a1d, actA, as_, ad_, N);
    agg_k<128><<<NWAVE, 256, 0, stream>>>(actA, as_, ad_, rowp, col, b1, actB, 0.01f, N);

    // ---- layer 2: 128 -> 64 ----
    gemm_att_k<128, 64><<<(N + 31) / 32, 256, 0, stream>>>(actB, W2, a2s, a2d, actA, as_, ad_, N);
    agg_k<64><<<NWAVE, 256, 0, stream>>>(actA, as_, ad_, rowp, col, b2, actB, 0.01f, N);

    // ---- layer 3: 64 -> 128 ----
    gemm_att_k<64, 128><<<(N + 63) / 64, 256, 0, stream>>>(actB, W3, a3s, a3d, actA, as_, ad_, N);
    agg_k<128><<<NWAVE, 256, 0, stream>>>(actA, as_, ad_, rowp, col, b3, actB, 0.01f, N);

    // ---- layer 4: 128 -> 32 ----
    gemm_att_k<128, 32><<<(N + 63) / 64, 256, 0, stream>>>(actB, W4, a4s, a4d, actA, as_, ad_, N);
    agg_k<32><<<NWAVE, 256, 0, stream>>>(actA, as_, ad_, rowp, col, b4, (float*)d_out, 1.0f, N);
}

// Round 3
// 373.688 us; speedup vs baseline: 1.6742x; 1.1038x over previous
//
#include <hip/hip_runtime.h>

#define NEG_ATT 0.2f

// ---------------- CSR build ----------------

__global__ __launch_bounds__(256) void init_cnt_k(int* cnt, int N) {
    int i = blockIdx.x * 256 + threadIdx.x;
    if (i < N) cnt[i] = 1;  // self-loop
}

__global__ __launch_bounds__(256) void count_k(const int* __restrict__ dst, int* cnt, int E) {
    int i = blockIdx.x * 256 + threadIdx.x;
    if (i < E) atomicAdd(&cnt[dst[i]], 1);
}

__global__ __launch_bounds__(256) void scan_block_k(const int* __restrict__ cnt, int* rowp, int* bsum, int N) {
    __shared__ int s[256];
    int t = threadIdx.x;
    int i = blockIdx.x * 256 + t;
    s[t] = (i < N) ? cnt[i] : 0;
    __syncthreads();
    #pragma unroll
    for (int off = 1; off < 256; off <<= 1) {
        int v = (t >= off) ? s[t - off] : 0;
        __syncthreads();
        s[t] += v;
        __syncthreads();
    }
    if (i < N) rowp[i + 1] = s[t];
    if (t == 255) bsum[blockIdx.x] = s[255];
}

__global__ void scan_bsum_k(int* bsum, int nb) {
    __shared__ int s[256];
    int t = threadIdx.x;
    s[t] = (t < nb) ? bsum[t] : 0;
    __syncthreads();
    if (t == 0) {
        int run = 0;
        for (int i = 0; i < nb; i++) { int v = s[i]; s[i] = run; run += v; }
    }
    __syncthreads();
    if (t < nb) bsum[t] = s[t];
}

__global__ __launch_bounds__(256) void add_off_k(int* rowp, const int* __restrict__ bsum, int* cnt, int N) {
    int i = blockIdx.x * 256 + threadIdx.x;
    if (i < N) { rowp[i + 1] += bsum[blockIdx.x]; cnt[i] = 0; }
    if (i == 0) rowp[0] = 0;
}

__global__ __launch_bounds__(256) void scatter_k(const int* __restrict__ src, const int* __restrict__ dst,
                                                 const int* __restrict__ rowp, int* cnt, int* col,
                                                 int E, int N) {
    int i = blockIdx.x * 256 + threadIdx.x;
    if (i < E) {
        int d = dst[i];
        int p = rowp[d] + atomicAdd(&cnt[d], 1);
        col[p] = src[i];
    } else if (i < E + N) {
        int d = i - E;
        int p = rowp[d] + atomicAdd(&cnt[d], 1);
        col[p] = d;
    }
}

// ---------------- wa = W @ a  (4 vectors of 64, both W are 64x128) ----------------

__global__ __launch_bounds__(256) void wa_k(const float* __restrict__ W1, const float* __restrict__ a1s,
                                            const float* __restrict__ a1d, const float* __restrict__ W3,
                                            const float* __restrict__ a3s, const float* __restrict__ a3d,
                                            float* __restrict__ wa /* [4][64] */) {
    int t = threadIdx.x;
    int ci = t & 63;
    int which = t >> 6;
    const float* W = (which < 2) ? W1 : W3;
    const float* a = (which == 0) ? a1s : (which == 1) ? a1d : (which == 2) ? a3s : a3d;
    float s = 0.f;
    for (int co = 0; co < 128; ++co) s += W[ci * 128 + co] * a[co];
    wa[t] = s;
}

// ---------------- GEMV: as_[n] = x[n,:].was, ad_[n] = x[n,:].wad  (CIN=64, wave/node) ----------------

__global__ __launch_bounds__(256) void gemv_k(const float* __restrict__ X, const float* __restrict__ was,
                                              const float* __restrict__ wad, float* __restrict__ as_,
                                              float* __restrict__ ad_, int N) {
    int wid  = (blockIdx.x * 256 + threadIdx.x) >> 6;
    int lane = threadIdx.x & 63;
    if (wid >= N) return;
    float xv = X[(size_t)wid * 64 + lane];
    float s1 = xv * was[lane];
    float s2 = xv * wad[lane];
    #pragma unroll
    for (int off = 32; off; off >>= 1) {
        s1 += __shfl_xor(s1, off);
        s2 += __shfl_xor(s2, off);
    }
    if (lane == 0) { as_[wid] = s1; ad_[wid] = s2; }
}

// ---------------- GEMM: H = X @ W, fp32, LDS-tiled, register tiling ----------------
// ATT epilogue: as_/ad_ = H row . a_s/a_d    (layers 2,4)
// BIASACT epilogue: H = leaky(H + bias)      (layers 1,3)

template <int CIN, int COUT, bool ATT, bool BIASACT>
__global__ __launch_bounds__(256) void gemm_k(const float* __restrict__ X, const float* __restrict__ W,
                                              const float* __restrict__ a_s, const float* __restrict__ a_d,
                                              const float* __restrict__ bias,
                                              float* __restrict__ H, float* __restrict__ as_,
                                              float* __restrict__ ad_, int N) {
    constexpr int RB  = (CIN == 128 && COUT == 64) ? 32 : 64;
    constexpr int NCT = COUT / 4;
    constexpr int NRT = 256 / NCT;
    constexpr int RT  = RB / NRT;
    __shared__ float Xs[RB][CIN];
    __shared__ float Ws[CIN][COUT];
    int tid  = threadIdx.x;
    int row0 = blockIdx.x * RB;

    for (int i = tid; i < CIN * COUT; i += 256) ((float*)Ws)[i] = W[i];
    for (int i = tid; i < RB * CIN; i += 256) {
        int r = i / CIN, k = i % CIN;
        int gr = row0 + r;
        ((float*)Xs)[i] = (gr < N) ? X[(size_t)gr * CIN + k] : 0.f;
    }
    __syncthreads();

    int ct = tid % NCT;
    int rt = tid / NCT;
    float acc[RT][4] = {};
    #pragma unroll 4
    for (int k = 0; k < CIN; ++k) {
        float w0 = Ws[k][ct];
        float w1 = Ws[k][ct + NCT];
        float w2 = Ws[k][ct + 2 * NCT];
        float w3 = Ws[k][ct + 3 * NCT];
        #pragma unroll
        for (int i = 0; i < RT; ++i) {
            float xv = Xs[rt + i * NRT][k];
            acc[i][0] += xv * w0;
            acc[i][1] += xv * w1;
            acc[i][2] += xv * w2;
            acc[i][3] += xv * w3;
        }
    }

    float asv[4], adv[4], bv[4];
    #pragma unroll
    for (int j = 0; j < 4; ++j) {
        if (ATT) { asv[j] = a_s[ct + j * NCT]; adv[j] = a_d[ct + j * NCT]; }
        if (BIASACT) bv[j] = bias[ct + j * NCT];
    }

    #pragma unroll
    for (int i = 0; i < RT; ++i) {
        int gr = row0 + rt + i * NRT;
        if (BIASACT) {
            #pragma unroll
            for (int j = 0; j < 4; ++j) {
                float v = acc[i][j] + bv[j];
                acc[i][j] = v > 0.f ? v : 0.01f * v;
            }
        }
        float s1 = 0.f, s2 = 0.f;
        if (ATT) {
            s1 = acc[i][0] * asv[0] + acc[i][1] * asv[1] + acc[i][2] * asv[2] + acc[i][3] * asv[3];
            s2 = acc[i][0] * adv[0] + acc[i][1] * adv[1] + acc[i][2] * adv[2] + acc[i][3] * adv[3];
            #pragma unroll
            for (int off = 1; off < NCT; off <<= 1) {
                s1 += __shfl_xor(s1, off);
                s2 += __shfl_xor(s2, off);
            }
        }
        if (gr < N) {
            #pragma unroll
            for (int j = 0; j < 4; ++j)
                H[(size_t)gr * COUT + ct + j * NCT] = acc[i][j];
            if (ATT && ct == 0) { as_[gr] = s1; ad_[gr] = s2; }
        }
    }
}

// ---------------- aggregate: out[d] = (sum_e softmax(e)*h[src_e]) [+b] [leaky] [gemv] ----------------
// MODE 0: plain weighted mean (pre-GEMM aggregation, layers 1,3)
// MODE 1: +bias +leaky(0.01) +fused GEMV for next layer's logits (layer 2)
// MODE 2: +bias (layer 4, final output)

template <int C, int MODE>
__global__ __launch_bounds__(256) void agg_k(const float* __restrict__ H, const float* __restrict__ as_,
                                             const float* __restrict__ ad_, const int* __restrict__ rowp,
                                             const int* __restrict__ col, const float* __restrict__ bias,
                                             const float* __restrict__ was, const float* __restrict__ wad,
                                             float* __restrict__ out, float* __restrict__ oas,
                                             float* __restrict__ oad, int N) {
    int wid  = (blockIdx.x * 256 + threadIdx.x) >> 6;
    int lane = threadIdx.x & 63;
    if (wid >= N) return;
    float adi = ad_[wid];
    int beg = rowp[wid], end = rowp[wid + 1];
    float denom = 0.f;
    float acc = 0.f;

    for (int base = beg; base < end; base += 64) {
        int cnt = end - base;
        if (cnt > 64) cnt = 64;
        int s_l = 0; float w_l = 0.f;
        if (lane < cnt) {
            s_l = col[base + lane];
            float e = as_[s_l] + adi;
            e = e > 0.f ? e : NEG_ATT * e;
            w_l = __expf(e);
        }
        denom += w_l;

        int j = 0;
        for (; j + 8 <= cnt; j += 8) {
            int ss[8]; float ww[8];
            #pragma unroll
            for (int u = 0; u < 8; ++u) {
                ss[u] = __shfl(s_l, j + u);
                ww[u] = __shfl(w_l, j + u);
            }
            if (lane < C) {
                float hv[8];
                #pragma unroll
                for (int u = 0; u < 8; ++u) hv[u] = H[(size_t)ss[u] * C + lane];
                #pragma unroll
                for (int u = 0; u < 8; ++u) acc += ww[u] * hv[u];
            }
        }
        for (; j < cnt; ++j) {
            int s = __shfl(s_l, j);
            float w = __shfl(w_l, j);
            if (lane < C) acc += w * H[(size_t)s * C + lane];
        }
    }

    #pragma unroll
    for (int off = 32; off; off >>= 1) denom += __shfl_xor(denom, off);

    float inv = 1.f / denom;
    float v = acc * inv;
    if (MODE == 1 || MODE == 2) v += (lane < C) ? bias[lane] : 0.f;
    if (MODE == 1) v = v > 0.f ? v : 0.01f * v;
    if (lane < C) out[(size_t)wid * C + lane] = v;

    if (MODE == 1) {
        // fused GEMV: next layer's logits from this row (C == 64)
        float s1 = v * was[lane];
        float s2 = v * wad[lane];
        #pragma unroll
        for (int off = 32; off; off >>= 1) {
            s1 += __shfl_xor(s1, off);
            s2 += __shfl_xor(s2, off);
        }
        if (lane == 0) { oas[wid] = s1; oad[wid] = s2; }
    }
}

// ---------------- launch ----------------

extern "C" void kernel_launch(void* const* d_in, const int* in_sizes, int n_in,
                              void* d_out, int out_size, void* d_ws, size_t ws_size,
                              hipStream_t stream) {
    const float* x  = (const float*)d_in[0];
    const int* ei   = (const int*)d_in[1];
    const float* W1 = (const float*)d_in[2];
    const float* a1s = (const float*)d_in[3];
    const float* a1d = (const float*)d_in[4];
    const float* b1  = (const float*)d_in[5];
    const float* W2 = (const float*)d_in[6];
    const float* a2s = (const float*)d_in[7];
    const float* a2d = (const float*)d_in[8];
    const float* b2  = (const float*)d_in[9];
    const float* W3 = (const float*)d_in[10];
    const float* a3s = (const float*)d_in[11];
    const float* a3d = (const float*)d_in[12];
    const float* b3  = (const float*)d_in[13];
    const float* W4 = (const float*)d_in[14];
    const float* a4s = (const float*)d_in[15];
    const float* a4d = (const float*)d_in[16];
    const float* b4  = (const float*)d_in[17];

    const int N = in_sizes[0] / 64;     // 50000
    const int E = in_sizes[1] / 2;      // 800000
    const int ET = E + N;
    const int* src = ei;
    const int* dst = ei + E;

    // workspace layout
    float* bufA = (float*)d_ws;             // N*128
    float* bufB = bufA + (size_t)N * 128;   // N*128
    float* asA  = bufB + (size_t)N * 128;   // N
    float* adA  = asA + N;                  // N
    float* asB  = adA + N;                  // N
    float* adB  = asB + N;                  // N
    float* wa   = adB + N;                  // 256 (4x64)
    int* cnt    = (int*)(wa + 256);         // N
    int* rowp   = cnt + N;                  // N+1
    int* col    = rowp + N + 1;             // ET
    int* bsum   = col + ET;                 // <=256

    const int NB = (N + 255) / 256;

    // ---- CSR build (dst-sorted), shared across all 4 layers ----
    init_cnt_k<<<NB, 256, 0, stream>>>(cnt, N);
    count_k<<<(E + 255) / 256, 256, 0, stream>>>(dst, cnt, E);
    scan_block_k<<<NB, 256, 0, stream>>>(cnt, rowp, bsum, N);
    scan_bsum_k<<<1, 256, 0, stream>>>(bsum, NB);
    add_off_k<<<NB, 256, 0, stream>>>(rowp, bsum, cnt, N);
    scatter_k<<<(ET + 255) / 256, 256, 0, stream>>>(src, dst, rowp, cnt, col, E, N);

    // ---- wa vectors for layers 1 and 3 (both W are 64x128) ----
    wa_k<<<1, 256, 0, stream>>>(W1, a1s, a1d, W3, a3s, a3d, wa);
    float* wa1s = wa, *wa1d = wa + 64, *wa3s = wa + 128, *wa3d = wa + 192;

    const int NWAVE = (N * 64 + 255) / 256;

    // ---- layer 1 (aggregate-first): T1 = Ahat1 @ x ; H1 = leaky(T1 @ W1 + b1) ----
    gemv_k<<<NWAVE, 256, 0, stream>>>(x, wa1s, wa1d, asA, adA, N);
    agg_k<64, 0><<<NWAVE, 256, 0, stream>>>(x, asA, adA, rowp, col, nullptr, nullptr, nullptr,
                                            bufA, nullptr, nullptr, N);
    gemm_k<64, 128, false, true><<<(N + 63) / 64, 256, 0, stream>>>(bufA, W1, nullptr, nullptr, b1,
                                                                    bufB, nullptr, nullptr, N);

    // ---- layer 2 (standard): H2 = H1 @ W2 (+logits) ; O2 = leaky(Ahat2 @ H2 + b2) (+logits L3) ----
    gemm_k<128, 64, true, false><<<(N + 31) / 32, 256, 0, stream>>>(bufB, W2, a2s, a2d, nullptr,
                                                                    bufA, asB, adB, N);
    agg_k<64, 1><<<NWAVE, 256, 0, stream>>>(bufA, asB, adB, rowp, col, b2, wa3s, wa3d,
                                            bufB, asA, adA, N);

    // ---- layer 3 (aggregate-first): T3 = Ahat3 @ O2 ; H3 = leaky(T3 @ W3 + b3) ----
    agg_k<64, 0><<<NWAVE, 256, 0, stream>>>(bufB, asA, adA, rowp, col, nullptr, nullptr, nullptr,
                                            bufA, nullptr, nullptr, N);
    gemm_k<64, 128, false, true><<<(N + 63) / 64, 256, 0, stream>>>(bufA, W3, nullptr, nullptr, b3,
                                                                    bufB, nullptr, nullptr, N);

    // ---- layer 4 (standard): H4 = H3 @ W4 (+logits) ; out = Ahat4 @ H4 + b4 ----
    gemm_k<128, 32, true, false><<<(N + 63) / 64, 256, 0, stream>>>(bufB, W4, a4s, a4d, nullptr,
                                                                    bufA, asB, adB, N);
    agg_k<32, 2><<<NWAVE, 256, 0, stream>>>(bufA, asB, adB, rowp, col, b4, nullptr, nullptr,
                                            (float*)d_out, nullptr, nullptr, N);
}

// Round 4
// 360.517 us; speedup vs baseline: 1.7354x; 1.0365x over previous
//
#include <hip/hip_runtime.h>

#define NEG_ATT 0.2f

__device__ __forceinline__ int rl_i(int v, int l) { return __builtin_amdgcn_readlane(v, l); }
__device__ __forceinline__ float rl_f(float v, int l) {
    return __int_as_float(__builtin_amdgcn_readlane(__float_as_int(v), l));
}

// ---------------- CSR build ----------------

__global__ __launch_bounds__(256) void init0_k(int* cnt, int N) {
    int i = blockIdx.x * 256 + threadIdx.x;
    if (i < N) cnt[i] = 0;
}

// off[i] = position of edge i within its dst segment (edges only; self-loop goes last)
__global__ __launch_bounds__(256) void countoff_k(const int* __restrict__ dst, int* cnt,
                                                  int* __restrict__ off, int E) {
    int i = blockIdx.x * 256 + threadIdx.x;
    if (i < E) off[i] = atomicAdd(&cnt[dst[i]], 1);
}

__global__ __launch_bounds__(256) void scan_block_k(const int* __restrict__ cnt, int* rowp, int* bsum, int N) {
    __shared__ int s[256];
    int t = threadIdx.x;
    int i = blockIdx.x * 256 + t;
    s[t] = (i < N) ? cnt[i] + 1 : 0;   // +1 for self-loop
    __syncthreads();
    #pragma unroll
    for (int off = 1; off < 256; off <<= 1) {
        int v = (t >= off) ? s[t - off] : 0;
        __syncthreads();
        s[t] += v;
        __syncthreads();
    }
    if (i < N) rowp[i + 1] = s[t];
    if (t == 255) bsum[blockIdx.x] = s[255];
}

__global__ void scan_bsum_k(int* bsum, int nb) {
    __shared__ int s[256];
    int t = threadIdx.x;
    s[t] = (t < nb) ? bsum[t] : 0;
    __syncthreads();
    if (t == 0) {
        int run = 0;
        for (int i = 0; i < nb; i++) { int v = s[i]; s[i] = run; run += v; }
    }
    __syncthreads();
    if (t < nb) bsum[t] = s[t];
}

__global__ __launch_bounds__(256) void add_off_k(int* rowp, const int* __restrict__ bsum, int N) {
    int i = blockIdx.x * 256 + threadIdx.x;
    if (i < N) rowp[i + 1] += bsum[blockIdx.x];
    if (i == 0) rowp[0] = 0;
}

__global__ __launch_bounds__(256) void scatter2_k(const int* __restrict__ src, const int* __restrict__ dst,
                                                  const int* __restrict__ rowp, const int* __restrict__ off,
                                                  int* __restrict__ col, int E) {
    int i = blockIdx.x * 256 + threadIdx.x;
    if (i < E) col[rowp[dst[i]] + off[i]] = src[i];
}

__global__ __launch_bounds__(256) void selfloop_k(const int* __restrict__ rowp, int* __restrict__ col, int N) {
    int i = blockIdx.x * 256 + threadIdx.x;
    if (i < N) col[rowp[i + 1] - 1] = i;
}

// ---------------- wa = W @ a  (4 vectors of 64, both W are 64x128) ----------------

__global__ __launch_bounds__(256) void wa_k(const float* __restrict__ W1, const float* __restrict__ a1s,
                                            const float* __restrict__ a1d, const float* __restrict__ W3,
                                            const float* __restrict__ a3s, const float* __restrict__ a3d,
                                            float* __restrict__ wa /* [4][64] */) {
    int t = threadIdx.x;
    int ci = t & 63;
    int which = t >> 6;
    const float* W = (which < 2) ? W1 : W3;
    const float* a = (which == 0) ? a1s : (which == 1) ? a1d : (which == 2) ? a3s : a3d;
    float s = 0.f;
    for (int co = 0; co < 128; ++co) s += W[ci * 128 + co] * a[co];
    wa[t] = s;
}

// ---------------- GEMV: as_[n] = x[n,:].was, ad_[n] = x[n,:].wad  (CIN=64, wave/node) ----------------

__global__ __launch_bounds__(256) void gemv_k(const float* __restrict__ X, const float* __restrict__ was,
                                              const float* __restrict__ wad, float* __restrict__ as_,
                                              float* __restrict__ ad_, int N) {
    int wid  = (blockIdx.x * 256 + threadIdx.x) >> 6;
    int lane = threadIdx.x & 63;
    if (wid >= N) return;
    float xv = X[(size_t)wid * 64 + lane];
    float s1 = xv * was[lane];
    float s2 = xv * wad[lane];
    #pragma unroll
    for (int off = 32; off; off >>= 1) {
        s1 += __shfl_xor(s1, off);
        s2 += __shfl_xor(s2, off);
    }
    if (lane == 0) { as_[wid] = s1; ad_[wid] = s2; }
}

// ---------------- GEMM: H = X @ W, fp32, LDS-tiled, register tiling ----------------

template <int CIN, int COUT, bool ATT, bool BIASACT>
__global__ __launch_bounds__(256) void gemm_k(const float* __restrict__ X, const float* __restrict__ W,
                                              const float* __restrict__ a_s, const float* __restrict__ a_d,
                                              const float* __restrict__ bias,
                                              float* __restrict__ H, float* __restrict__ as_,
                                              float* __restrict__ ad_, int N) {
    constexpr int RB  = (CIN == 128 && COUT == 64) ? 32 : 64;
    constexpr int NCT = COUT / 4;
    constexpr int NRT = 256 / NCT;
    constexpr int RT  = RB / NRT;
    __shared__ float Xs[RB][CIN];
    __shared__ float Ws[CIN][COUT];
    int tid  = threadIdx.x;
    int row0 = blockIdx.x * RB;

    for (int i = tid; i < CIN * COUT; i += 256) ((float*)Ws)[i] = W[i];
    for (int i = tid; i < RB * CIN; i += 256) {
        int r = i / CIN, k = i % CIN;
        int gr = row0 + r;
        ((float*)Xs)[i] = (gr < N) ? X[(size_t)gr * CIN + k] : 0.f;
    }
    __syncthreads();

    int ct = tid % NCT;
    int rt = tid / NCT;
    float acc[RT][4] = {};
    #pragma unroll 4
    for (int k = 0; k < CIN; ++k) {
        float w0 = Ws[k][ct];
        float w1 = Ws[k][ct + NCT];
        float w2 = Ws[k][ct + 2 * NCT];
        float w3 = Ws[k][ct + 3 * NCT];
        #pragma unroll
        for (int i = 0; i < RT; ++i) {
            float xv = Xs[rt + i * NRT][k];
            acc[i][0] += xv * w0;
            acc[i][1] += xv * w1;
            acc[i][2] += xv * w2;
            acc[i][3] += xv * w3;
        }
    }

    float asv[4], adv[4], bv[4];
    #pragma unroll
    for (int j = 0; j < 4; ++j) {
        if (ATT) { asv[j] = a_s[ct + j * NCT]; adv[j] = a_d[ct + j * NCT]; }
        if (BIASACT) bv[j] = bias[ct + j * NCT];
    }

    #pragma unroll
    for (int i = 0; i < RT; ++i) {
        int gr = row0 + rt + i * NRT;
        if (BIASACT) {
            #pragma unroll
            for (int j = 0; j < 4; ++j) {
                float v = acc[i][j] + bv[j];
                acc[i][j] = v > 0.f ? v : 0.01f * v;
            }
        }
        float s1 = 0.f, s2 = 0.f;
        if (ATT) {
            s1 = acc[i][0] * asv[0] + acc[i][1] * asv[1] + acc[i][2] * asv[2] + acc[i][3] * asv[3];
            s2 = acc[i][0] * adv[0] + acc[i][1] * adv[1] + acc[i][2] * adv[2] + acc[i][3] * adv[3];
            #pragma unroll
            for (int off = 1; off < NCT; off <<= 1) {
                s1 += __shfl_xor(s1, off);
                s2 += __shfl_xor(s2, off);
            }
        }
        if (gr < N) {
            #pragma unroll
            for (int j = 0; j < 4; ++j)
                H[(size_t)gr * COUT + ct + j * NCT] = acc[i][j];
            if (ATT && ct == 0) { as_[gr] = s1; ad_[gr] = s2; }
        }
    }
}

// ---------------- aggregate ----------------
// MODE 0: plain weighted mean (C=64)
// MODE 1: +bias +leaky(0.01) +fused GEMV for next layer's logits (C=64)
// MODE 2: +bias, C=32 (final output; two edge-rows gathered per wave)

template <int C, int MODE>
__global__ __launch_bounds__(256) void agg_k(const float* __restrict__ H, const float* __restrict__ as_,
                                             const float* __restrict__ ad_, const int* __restrict__ rowp,
                                             const int* __restrict__ col, const float* __restrict__ bias,
                                             const float* __restrict__ was, const float* __restrict__ wad,
                                             float* __restrict__ out, float* __restrict__ oas,
                                             float* __restrict__ oad, int N) {
    int wid  = (blockIdx.x * 256 + threadIdx.x) >> 6;
    int lane = threadIdx.x & 63;
    if (wid >= N) return;
    float adi = ad_[wid];
    int beg = rowp[wid], end = rowp[wid + 1];
    float denom = 0.f;
    float acc = 0.f;
    const int sub = lane >> 5;
    const int c32 = lane & 31;

    for (int base = beg; base < end; base += 64) {
        int cnt = end - base;
        if (cnt > 64) cnt = 64;
        int s_l = 0; float w_l = 0.f;
        if (lane < cnt) {
            s_l = col[base + lane];
            float e = as_[s_l] + adi;
            e = e > 0.f ? e : NEG_ATT * e;
            w_l = __expf(e);
        }
        denom += w_l;

        if (C == 64) {
            int j = 0;
            for (; j + 16 <= cnt; j += 16) {
                float hv[16], wv[16];
                #pragma unroll
                for (int u = 0; u < 16; ++u) {
                    int s = rl_i(s_l, j + u);
                    wv[u] = rl_f(w_l, j + u);
                    hv[u] = H[(s << 6) | lane];
                }
                #pragma unroll
                for (int u = 0; u < 16; ++u) acc += wv[u] * hv[u];
            }
            for (; j < cnt; ++j) {
                int s = rl_i(s_l, j);
                float w = rl_f(w_l, j);
                acc += w * H[(s << 6) | lane];
            }
        } else {  // C == 32: lanes 0-31 take even edges, 32-63 odd
            int j = 0;
            for (; j + 16 <= cnt; j += 16) {
                float hv[8], wv[8];
                #pragma unroll
                for (int u = 0; u < 8; ++u) {
                    int s0 = rl_i(s_l, j + 2 * u);
                    int s1 = rl_i(s_l, j + 2 * u + 1);
                    float w0 = rl_f(w_l, j + 2 * u);
                    float w1 = rl_f(w_l, j + 2 * u + 1);
                    int s = sub ? s1 : s0;
                    wv[u] = sub ? w1 : w0;
                    hv[u] = H[(s << 5) | c32];
                }
                #pragma unroll
                for (int u = 0; u < 8; ++u) acc += wv[u] * hv[u];
            }
            for (; j + 2 <= cnt; j += 2) {
                int s0 = rl_i(s_l, j);
                int s1 = rl_i(s_l, j + 1);
                float w0 = rl_f(w_l, j);
                float w1 = rl_f(w_l, j + 1);
                int s = sub ? s1 : s0;
                float w = sub ? w1 : w0;
                acc += w * H[(s << 5) | c32];
            }
            if (j < cnt) {
                int s = rl_i(s_l, j);
                float w = rl_f(w_l, j);
                if (!sub) acc += w * H[(s << 5) | c32];
            }
        }
    }

    #pragma unroll
    for (int off = 32; off; off >>= 1) denom += __shfl_xor(denom, off);
    if (C == 32) acc += __shfl_xor(acc, 32);  // fold the two edge-halves

    float inv = 1.f / denom;
    float v = acc * inv;
    if (MODE == 1) {
        v += bias[lane];
        v = v > 0.f ? v : 0.01f * v;
        out[((size_t)wid << 6) | lane] = v;
        // fused GEMV: next layer's logits from this row
        float s1 = v * was[lane];
        float s2 = v * wad[lane];
        #pragma unroll
        for (int off = 32; off; off >>= 1) {
            s1 += __shfl_xor(s1, off);
            s2 += __shfl_xor(s2, off);
        }
        if (lane == 0) { oas[wid] = s1; oad[wid] = s2; }
    } else if (MODE == 2) {
        if (lane < 32) out[((size_t)wid << 5) | c32] = v + bias[c32];
    } else {
        out[((size_t)wid << 6) | lane] = v;
    }
}

// ---------------- launch ----------------

extern "C" void kernel_launch(void* const* d_in, const int* in_sizes, int n_in,
                              void* d_out, int out_size, void* d_ws, size_t ws_size,
                              hipStream_t stream) {
    const float* x  = (const float*)d_in[0];
    const int* ei   = (const int*)d_in[1];
    const float* W1 = (const float*)d_in[2];
    const float* a1s = (const float*)d_in[3];
    const float* a1d = (const float*)d_in[4];
    const float* b1  = (const float*)d_in[5];
    const float* W2 = (const float*)d_in[6];
    const float* a2s = (const float*)d_in[7];
    const float* a2d = (const float*)d_in[8];
    const float* b2  = (const float*)d_in[9];
    const float* W3 = (const float*)d_in[10];
    const float* a3s = (const float*)d_in[11];
    const float* a3d = (const float*)d_in[12];
    const float* b3  = (const float*)d_in[13];
    const float* W4 = (const float*)d_in[14];
    const float* a4s = (const float*)d_in[15];
    const float* a4d = (const float*)d_in[16];
    const float* b4  = (const float*)d_in[17];

    const int N = in_sizes[0] / 64;     // 50000
    const int E = in_sizes[1] / 2;      // 800000
    const int ET = E + N;
    const int* src = ei;
    const int* dst = ei + E;

    // workspace layout
    float* bufA = (float*)d_ws;             // N*128
    float* bufB = bufA + (size_t)N * 128;   // N*128
    float* asA  = bufB + (size_t)N * 128;   // N
    float* adA  = asA + N;                  // N
    float* asB  = adA + N;                  // N
    float* adB  = asB + N;                  // N
    float* wa   = adB + N;                  // 256 (4x64)
    int* cnt    = (int*)(wa + 256);         // N
    int* rowp   = cnt + N;                  // N+1
    int* col    = rowp + N + 1;             // ET
    int* bsum   = col + ET;                 // <=256
    int* off    = (int*)bufA;               // E ints, aliased (CSR build precedes layer 1)

    const int NB = (N + 255) / 256;
    const int EB = (E + 255) / 256;

    // ---- CSR build (dst-sorted), shared across all 4 layers ----
    init0_k<<<NB, 256, 0, stream>>>(cnt, N);
    countoff_k<<<EB, 256, 0, stream>>>(dst, cnt, off, E);
    scan_block_k<<<NB, 256, 0, stream>>>(cnt, rowp, bsum, N);
    scan_bsum_k<<<1, 256, 0, stream>>>(bsum, NB);
    add_off_k<<<NB, 256, 0, stream>>>(rowp, bsum, N);
    scatter2_k<<<EB, 256, 0, stream>>>(src, dst, rowp, off, col, E);
    selfloop_k<<<NB, 256, 0, stream>>>(rowp, col, N);

    // ---- wa vectors for layers 1 and 3 (both W are 64x128) ----
    wa_k<<<1, 256, 0, stream>>>(W1, a1s, a1d, W3, a3s, a3d, wa);
    float* wa1s = wa, *wa1d = wa + 64, *wa3s = wa + 128, *wa3d = wa + 192;

    const int NWAVE = (N * 64 + 255) / 256;

    // ---- layer 1 (aggregate-first): T1 = Ahat1 @ x ; H1 = leaky(T1 @ W1 + b1) ----
    gemv_k<<<NWAVE, 256, 0, stream>>>(x, wa1s, wa1d, asA, adA, N);
    agg_k<64, 0><<<NWAVE, 256, 0, stream>>>(x, asA, adA, rowp, col, nullptr, nullptr, nullptr,
                                            bufA, nullptr, nullptr, N);
    gemm_k<64, 128, false, true><<<(N + 63) / 64, 256, 0, stream>>>(bufA, W1, nullptr, nullptr, b1,
                                                                    bufB, nullptr, nullptr, N);

    // ---- layer 2 (standard): H2 = H1 @ W2 (+logits) ; O2 = leaky(Ahat2 @ H2 + b2) (+logits L3) ----
    gemm_k<128, 64, true, false><<<(N + 31) / 32, 256, 0, stream>>>(bufB, W2, a2s, a2d, nullptr,
                                                                    bufA, asB, adB, N);
    agg_k<64, 1><<<NWAVE, 256, 0, stream>>>(bufA, asB, adB, rowp, col, b2, wa3s, wa3d,
                                            bufB, asA, adA, N);

    // ---- layer 3 (aggregate-first): T3 = Ahat3 @ O2 ; H3 = leaky(T3 @ W3 + b3) ----
    agg_k<64, 0><<<NWAVE, 256, 0, stream>>>(bufB, asA, adA, rowp, col, nullptr, nullptr, nullptr,
                                            bufA, nullptr, nullptr, N);
    gemm_k<64, 128, false, true><<<(N + 63) / 64, 256, 0, stream>>>(bufA, W3, nullptr, nullptr, b3,
                                                                    bufB, nullptr, nullptr, N);

    // ---- layer 4 (standard): H4 = H3 @ W4 (+logits) ; out = Ahat4 @ H4 + b4 ----
    gemm_k<128, 32, true, false><<<(N + 63) / 64, 256, 0, stream>>>(bufB, W4, a4s, a4d, nullptr,
                                                                    bufA, asB, adB, N);
    agg_k<32, 2><<<NWAVE, 256, 0, stream>>>(bufA, asB, adB, rowp, col, b4, nullptr, nullptr,
                                            (float*)d_out, nullptr, nullptr, N);
}

// Round 5
// 321.548 us; speedup vs baseline: 1.9457x; 1.1212x over previous
//
#include <hip/hip_runtime.h>

#define NEG_ATT 0.2f

__device__ __forceinline__ int rl_i(int v, int l) { return __builtin_amdgcn_readlane(v, l); }
__device__ __forceinline__ float rl_f(float v, int l) {
    return __int_as_float(__builtin_amdgcn_readlane(__float_as_int(v), l));
}

// ---------------- CSR build ----------------

// off[i] = position of edge i within its dst segment (edges only; self-loop goes last)
__global__ __launch_bounds__(256) void countoff_k(const int* __restrict__ dst, int* cnt,
                                                  int* __restrict__ off, int E) {
    int i = blockIdx.x * 256 + threadIdx.x;
    if (i < E) off[i] = atomicAdd(&cnt[dst[i]], 1);
}

__global__ __launch_bounds__(256) void scan_block_k(const int* __restrict__ cnt, int* rowp, int* bsum, int N) {
    __shared__ int s[256];
    int t = threadIdx.x;
    int i = blockIdx.x * 256 + t;
    s[t] = (i < N) ? cnt[i] + 1 : 0;   // +1 for self-loop
    __syncthreads();
    #pragma unroll
    for (int off = 1; off < 256; off <<= 1) {
        int v = (t >= off) ? s[t - off] : 0;
        __syncthreads();
        s[t] += v;
        __syncthreads();
    }
    if (i < N) rowp[i + 1] = s[t];
    if (t == 255) bsum[blockIdx.x] = s[255];
}

__global__ void scan_bsum_k(int* bsum, int nb) {
    __shared__ int s[256];
    int t = threadIdx.x;
    s[t] = (t < nb) ? bsum[t] : 0;
    __syncthreads();
    if (t == 0) {
        int run = 0;
        for (int i = 0; i < nb; i++) { int v = s[i]; s[i] = run; run += v; }
    }
    __syncthreads();
    if (t < nb) bsum[t] = s[t];
}

__global__ __launch_bounds__(256) void add_off_k(int* rowp, const int* __restrict__ bsum, int N) {
    int i = blockIdx.x * 256 + threadIdx.x;
    if (i < N) rowp[i + 1] += bsum[blockIdx.x];
    if (i == 0) rowp[0] = 0;
}

// scatter edges + self-loops (self-loop at segment end)
__global__ __launch_bounds__(256) void scatter2_k(const int* __restrict__ src, const int* __restrict__ dst,
                                                  const int* __restrict__ rowp, const int* __restrict__ off,
                                                  int* __restrict__ col, int E, int N) {
    int i = blockIdx.x * 256 + threadIdx.x;
    if (i < E) {
        col[rowp[dst[i]] + off[i]] = src[i];
    } else if (i < E + N) {
        int d = i - E;
        col[rowp[d + 1] - 1] = d;
    }
}

// ---------------- setup: zero cnt + wa = W @ a (4 vectors of 64) ----------------

__global__ __launch_bounds__(256) void setup_k(int* cnt, int N, int NB,
                                               const float* __restrict__ W1, const float* __restrict__ a1s,
                                               const float* __restrict__ a1d, const float* __restrict__ W3,
                                               const float* __restrict__ a3s, const float* __restrict__ a3d,
                                               float* __restrict__ wa /* [4][64] */) {
    int b = blockIdx.x;
    if (b < NB) {
        int i = b * 256 + threadIdx.x;
        if (i < N) cnt[i] = 0;
    } else {
        int t = threadIdx.x;
        int ci = t & 63;
        int which = t >> 6;
        const float* W = (which < 2) ? W1 : W3;
        const float* a = (which == 0) ? a1s : (which == 1) ? a1d : (which == 2) ? a3s : a3d;
        float s = 0.f;
        for (int co = 0; co < 128; ++co) s += W[ci * 128 + co] * a[co];
        wa[t] = s;
    }
}

// ---------------- GEMV: as_[n] = x[n,:].was, ad_[n] = x[n,:].wad  (CIN=64, wave/node) ----------------

__global__ __launch_bounds__(256) void gemv_k(const float* __restrict__ X, const float* __restrict__ was,
                                              const float* __restrict__ wad, float* __restrict__ as_,
                                              float* __restrict__ ad_, int N) {
    int wid  = (blockIdx.x * 256 + threadIdx.x) >> 6;
    int lane = threadIdx.x & 63;
    if (wid >= N) return;
    float xv = X[(size_t)wid * 64 + lane];
    float s1 = xv * was[lane];
    float s2 = xv * wad[lane];
    #pragma unroll
    for (int off = 32; off; off >>= 1) {
        s1 += __shfl_xor(s1, off);
        s2 += __shfl_xor(s2, off);
    }
    if (lane == 0) { as_[wid] = s1; ad_[wid] = s2; }
}

// ---------------- GEMM: H = X @ W, fp32, LDS-tiled, register tiling ----------------

template <int CIN, int COUT, bool ATT, bool BIASACT>
__global__ __launch_bounds__(256) void gemm_k(const float* __restrict__ X, const float* __restrict__ W,
                                              const float* __restrict__ a_s, const float* __restrict__ a_d,
                                              const float* __restrict__ bias,
                                              float* __restrict__ H, float* __restrict__ as_,
                                              float* __restrict__ ad_, int N) {
    constexpr int RB  = (CIN == 128 && COUT == 64) ? 32 : 64;
    constexpr int NCT = COUT / 4;
    constexpr int NRT = 256 / NCT;
    constexpr int RT  = RB / NRT;
    __shared__ float Xs[RB][CIN];
    __shared__ float Ws[CIN][COUT];
    int tid  = threadIdx.x;
    int row0 = blockIdx.x * RB;

    for (int i = tid; i < CIN * COUT; i += 256) ((float*)Ws)[i] = W[i];
    for (int i = tid; i < RB * CIN; i += 256) {
        int r = i / CIN, k = i % CIN;
        int gr = row0 + r;
        ((float*)Xs)[i] = (gr < N) ? X[(size_t)gr * CIN + k] : 0.f;
    }
    __syncthreads();

    int ct = tid % NCT;
    int rt = tid / NCT;
    float acc[RT][4] = {};
    #pragma unroll 4
    for (int k = 0; k < CIN; ++k) {
        float w0 = Ws[k][ct];
        float w1 = Ws[k][ct + NCT];
        float w2 = Ws[k][ct + 2 * NCT];
        float w3 = Ws[k][ct + 3 * NCT];
        #pragma unroll
        for (int i = 0; i < RT; ++i) {
            float xv = Xs[rt + i * NRT][k];
            acc[i][0] += xv * w0;
            acc[i][1] += xv * w1;
            acc[i][2] += xv * w2;
            acc[i][3] += xv * w3;
        }
    }

    float asv[4], adv[4], bv[4];
    #pragma unroll
    for (int j = 0; j < 4; ++j) {
        if (ATT) { asv[j] = a_s[ct + j * NCT]; adv[j] = a_d[ct + j * NCT]; }
        if (BIASACT) bv[j] = bias[ct + j * NCT];
    }

    #pragma unroll
    for (int i = 0; i < RT; ++i) {
        int gr = row0 + rt + i * NRT;
        if (BIASACT) {
            #pragma unroll
            for (int j = 0; j < 4; ++j) {
                float v = acc[i][j] + bv[j];
                acc[i][j] = v > 0.f ? v : 0.01f * v;
            }
        }
        float s1 = 0.f, s2 = 0.f;
        if (ATT) {
            s1 = acc[i][0] * asv[0] + acc[i][1] * asv[1] + acc[i][2] * asv[2] + acc[i][3] * asv[3];
            s2 = acc[i][0] * adv[0] + acc[i][1] * adv[1] + acc[i][2] * adv[2] + acc[i][3] * adv[3];
            #pragma unroll
            for (int off = 1; off < NCT; off <<= 1) {
                s1 += __shfl_xor(s1, off);
                s2 += __shfl_xor(s2, off);
            }
        }
        if (gr < N) {
            #pragma unroll
            for (int j = 0; j < 4; ++j)
                H[(size_t)gr * COUT + ct + j * NCT] = acc[i][j];
            if (ATT && ct == 0) { as_[gr] = s1; ad_[gr] = s2; }
        }
    }
}

// ---------------- aggregate ----------------
// MODE 0: plain weighted mean (C=64)
// MODE 1: +bias +leaky(0.01) +fused GEMV for next layer's logits (C=64)
// MODE 2: +bias, C=32 (final output; two edge-rows gathered per wave)
// Gather batches are PADDED to 16 edges: inactive lanes hold s=0, w=0, so
// padded slots gather the L1-hot H[0] row with zero weight (exact no-op).

template <int C, int MODE>
__global__ __launch_bounds__(256) void agg_k(const float* __restrict__ H, const float* __restrict__ as_,
                                             const float* __restrict__ ad_, const int* __restrict__ rowp,
                                             const int* __restrict__ col, const float* __restrict__ bias,
                                             const float* __restrict__ was, const float* __restrict__ wad,
                                             float* __restrict__ out, float* __restrict__ oas,
                                             float* __restrict__ oad, int N) {
    int wid  = (blockIdx.x * 256 + threadIdx.x) >> 6;
    int lane = threadIdx.x & 63;
    if (wid >= N) return;
    float adi = ad_[wid];
    int beg = rowp[wid], end = rowp[wid + 1];
    float denom = 0.f;
    float a0 = 0.f, a1 = 0.f, a2 = 0.f, a3 = 0.f;
    const int sub = lane >> 5;
    const int c32 = lane & 31;

    for (int base = beg; base < end; base += 64) {
        int cnt = end - base;
        if (cnt > 64) cnt = 64;
        int s_l = 0; float w_l = 0.f;
        if (lane < cnt) {
            s_l = col[base + lane];
            float e = as_[s_l] + adi;
            e = e > 0.f ? e : NEG_ATT * e;
            w_l = __expf(e);
        }
        denom += w_l;

        int nb = (cnt + 15) >> 4;  // full 16-edge batches, padded
        if (C == 64) {
            for (int b = 0; b < nb; ++b) {
                int j = b << 4;
                float hv[16], wv[16];
                #pragma unroll
                for (int u = 0; u < 16; ++u) {
                    int s = rl_i(s_l, j + u);
                    wv[u] = rl_f(w_l, j + u);
                    hv[u] = H[(s << 6) | lane];
                }
                #pragma unroll
                for (int u = 0; u < 16; u += 4) {
                    a0 += wv[u] * hv[u];
                    a1 += wv[u + 1] * hv[u + 1];
                    a2 += wv[u + 2] * hv[u + 2];
                    a3 += wv[u + 3] * hv[u + 3];
                }
            }
        } else {  // C == 32: lanes 0-31 take even edges, 32-63 odd
            for (int b = 0; b < nb; ++b) {
                int j = b << 4;
                float hv[8], wv[8];
                #pragma unroll
                for (int u = 0; u < 8; ++u) {
                    int s0 = rl_i(s_l, j + 2 * u);
                    int s1 = rl_i(s_l, j + 2 * u + 1);
                    float w0 = rl_f(w_l, j + 2 * u);
                    float w1 = rl_f(w_l, j + 2 * u + 1);
                    int s = sub ? s1 : s0;
                    wv[u] = sub ? w1 : w0;
                    hv[u] = H[(s << 5) | c32];
                }
                #pragma unroll
                for (int u = 0; u < 8; u += 2) {
                    a0 += wv[u] * hv[u];
                    a1 += wv[u + 1] * hv[u + 1];
                }
            }
        }
    }

    float acc = (a0 + a1) + (a2 + a3);
    #pragma unroll
    for (int off = 32; off; off >>= 1) denom += __shfl_xor(denom, off);
    if (C == 32) acc += __shfl_xor(acc, 32);  // fold the two edge-halves

    float inv = 1.f / denom;
    float v = acc * inv;
    if (MODE == 1) {
        v += bias[lane];
        v = v > 0.f ? v : 0.01f * v;
        out[((size_t)wid << 6) | lane] = v;
        // fused GEMV: next layer's logits from this row
        float s1 = v * was[lane];
        float s2 = v * wad[lane];
        #pragma unroll
        for (int off = 32; off; off >>= 1) {
            s1 += __shfl_xor(s1, off);
            s2 += __shfl_xor(s2, off);
        }
        if (lane == 0) { oas[wid] = s1; oad[wid] = s2; }
    } else if (MODE == 2) {
        if (lane < 32) out[((size_t)wid << 5) | c32] = v + bias[c32];
    } else {
        out[((size_t)wid << 6) | lane] = v;
    }
}

// ---------------- launch ----------------

extern "C" void kernel_launch(void* const* d_in, const int* in_sizes, int n_in,
                              void* d_out, int out_size, void* d_ws, size_t ws_size,
                              hipStream_t stream) {
    const float* x  = (const float*)d_in[0];
    const int* ei   = (const int*)d_in[1];
    const float* W1 = (const float*)d_in[2];
    const float* a1s = (const float*)d_in[3];
    const float* a1d = (const float*)d_in[4];
    const float* b1  = (const float*)d_in[5];
    const float* W2 = (const float*)d_in[6];
    const float* a2s = (const float*)d_in[7];
    const float* a2d = (const float*)d_in[8];
    const float* b2  = (const float*)d_in[9];
    const float* W3 = (const float*)d_in[10];
    const float* a3s = (const float*)d_in[11];
    const float* a3d = (const float*)d_in[12];
    const float* b3  = (const float*)d_in[13];
    const float* W4 = (const float*)d_in[14];
    const float* a4s = (const float*)d_in[15];
    const float* a4d = (const float*)d_in[16];
    const float* b4  = (const float*)d_in[17];

    const int N = in_sizes[0] / 64;     // 50000
    const int E = in_sizes[1] / 2;      // 800000
    const int ET = E + N;
    const int* src = ei;
    const int* dst = ei + E;

    // workspace layout
    float* bufA = (float*)d_ws;             // N*128
    float* bufB = bufA + (size_t)N * 128;   // N*128
    float* asA  = bufB + (size_t)N * 128;   // N
    float* adA  = asA + N;                  // N
    float* asB  = adA + N;                  // N
    float* adB  = asB + N;                  // N
    float* wa   = adB + N;                  // 256 (4x64)
    int* cnt    = (int*)(wa + 256);         // N
    int* rowp   = cnt + N;                  // N+1
    int* col    = rowp + N + 1;             // ET
    int* bsum   = col + ET;                 // <=256
    int* off    = (int*)bufA;               // E ints, aliased (CSR build precedes layer 1)

    const int NB = (N + 255) / 256;
    const int EB = (E + 255) / 256;

    // ---- setup: zero cnt + wa vectors (one kernel) ----
    setup_k<<<NB + 1, 256, 0, stream>>>(cnt, N, NB, W1, a1s, a1d, W3, a3s, a3d, wa);
    float* wa1s = wa, *wa1d = wa + 64, *wa3s = wa + 128, *wa3d = wa + 192;

    // ---- CSR build (dst-sorted), shared across all 4 layers ----
    countoff_k<<<EB, 256, 0, stream>>>(dst, cnt, off, E);
    scan_block_k<<<NB, 256, 0, stream>>>(cnt, rowp, bsum, N);
    scan_bsum_k<<<1, 256, 0, stream>>>(bsum, NB);
    add_off_k<<<NB, 256, 0, stream>>>(rowp, bsum, N);
    scatter2_k<<<(ET + 255) / 256, 256, 0, stream>>>(src, dst, rowp, off, col, E, N);

    const int NWAVE = (N * 64 + 255) / 256;

    // ---- layer 1 (aggregate-first): T1 = Ahat1 @ x ; H1 = leaky(T1 @ W1 + b1) ----
    gemv_k<<<NWAVE, 256, 0, stream>>>(x, wa1s, wa1d, asA, adA, N);
    agg_k<64, 0><<<NWAVE, 256, 0, stream>>>(x, asA, adA, rowp, col, nullptr, nullptr, nullptr,
                                            bufA, nullptr, nullptr, N);
    gemm_k<64, 128, false, true><<<(N + 63) / 64, 256, 0, stream>>>(bufA, W1, nullptr, nullptr, b1,
                                                                    bufB, nullptr, nullptr, N);

    // ---- layer 2 (standard): H2 = H1 @ W2 (+logits) ; O2 = leaky(Ahat2 @ H2 + b2) (+logits L3) ----
    gemm_k<128, 64, true, false><<<(N + 31) / 32, 256, 0, stream>>>(bufB, W2, a2s, a2d, nullptr,
                                                                    bufA, asB, adB, N);
    agg_k<64, 1><<<NWAVE, 256, 0, stream>>>(bufA, asB, adB, rowp, col, b2, wa3s, wa3d,
                                            bufB, asA, adA, N);

    // ---- layer 3 (aggregate-first): T3 = Ahat3 @ O2 ; H3 = leaky(T3 @ W3 + b3) ----
    agg_k<64, 0><<<NWAVE, 256, 0, stream>>>(bufB, asA, adA, rowp, col, nullptr, nullptr, nullptr,
                                            bufA, nullptr, nullptr, N);
    gemm_k<64, 128, false, true><<<(N + 63) / 64, 256, 0, stream>>>(bufA, W3, nullptr, nullptr, b3,
                                                                    bufB, nullptr, nullptr, N);

    // ---- layer 4 (standard): H4 = H3 @ W4 (+logits) ; out = Ahat4 @ H4 + b4 ----
    gemm_k<128, 32, true, false><<<(N + 63) / 64, 256, 0, stream>>>(bufB, W4, a4s, a4d, nullptr,
                                                                    bufA, asB, adB, N);
    agg_k<32, 2><<<NWAVE, 256, 0, stream>>>(bufA, asB, adB, rowp, col, b4, nullptr, nullptr,
                                            (float*)d_out, nullptr, nullptr, N);
}

// Round 6
// 300.202 us; speedup vs baseline: 2.0840x; 1.0711x over previous
//
#include <hip/hip_runtime.h>

#define NEG_ATT 0.2f

// ---------------- CSR build (XCD-partitioned: blockIdx&7 -> dst range) ----------------

__global__ __launch_bounds__(256) void count_k(const int* __restrict__ dst, int* cnt, int E, int step) {
    int part = blockIdx.x & 7;
    int i = (blockIdx.x >> 3) * 256 + threadIdx.x;
    int lo = part * step, hi = lo + step;
    if (i < E) {
        int d = dst[i];
        if (d >= lo && d < hi) atomicAdd(&cnt[d], 1);
    }
}

__global__ __launch_bounds__(256) void scan_block_k(const int* __restrict__ cnt, int* rowp, int* bsum, int N) {
    __shared__ int s[256];
    int t = threadIdx.x;
    int i = blockIdx.x * 256 + t;
    s[t] = (i < N) ? cnt[i] + 1 : 0;   // +1 for self-loop
    __syncthreads();
    #pragma unroll
    for (int off = 1; off < 256; off <<= 1) {
        int v = (t >= off) ? s[t - off] : 0;
        __syncthreads();
        s[t] += v;
        __syncthreads();
    }
    if (i < N) rowp[i + 1] = s[t];
    if (t == 255) bsum[blockIdx.x] = s[255];
}

__global__ void scan_bsum_k(int* bsum, int nb) {
    __shared__ int s[256];
    int t = threadIdx.x;
    s[t] = (t < nb) ? bsum[t] : 0;
    __syncthreads();
    if (t == 0) {
        int run = 0;
        for (int i = 0; i < nb; i++) { int v = s[i]; s[i] = run; run += v; }
    }
    __syncthreads();
    if (t < nb) bsum[t] = s[t];
}

__global__ __launch_bounds__(256) void add_off_k(int* rowp, const int* __restrict__ bsum, int* cnt, int N) {
    int i = blockIdx.x * 256 + threadIdx.x;
    if (i < N) { rowp[i + 1] += bsum[blockIdx.x]; cnt[i] = 0; }
    if (i == 0) rowp[0] = 0;
}

// scatter edges + self-loops, XCD-partitioned (atomics + col writes stay L2-local)
__global__ __launch_bounds__(256) void scatter_k(const int* __restrict__ src, const int* __restrict__ dst,
                                                 const int* __restrict__ rowp, int* cnt,
                                                 int* __restrict__ col, int E, int N, int step) {
    int part = blockIdx.x & 7;
    int i = (blockIdx.x >> 3) * 256 + threadIdx.x;
    int lo = part * step, hi = lo + step;
    if (i < E) {
        int d = dst[i];
        if (d >= lo && d < hi) {
            int p = rowp[d] + atomicAdd(&cnt[d], 1);
            col[p] = src[i];
        }
    } else if (i < E + N) {
        int d = i - E;
        if (d >= lo && d < hi) col[rowp[d + 1] - 1] = d;
    }
}

// ---------------- setup: zero cnt + wa = W @ a (4 vectors of 64) ----------------

__global__ __launch_bounds__(256) void setup_k(int* cnt, int N, int NB,
                                               const float* __restrict__ W1, const float* __restrict__ a1s,
                                               const float* __restrict__ a1d, const float* __restrict__ W3,
                                               const float* __restrict__ a3s, const float* __restrict__ a3d,
                                               float* __restrict__ wa /* [4][64] */) {
    int b = blockIdx.x;
    if (b < NB) {
        int i = b * 256 + threadIdx.x;
        if (i < N) cnt[i] = 0;
    } else {
        int t = threadIdx.x;
        int ci = t & 63;
        int which = t >> 6;
        const float* W = (which < 2) ? W1 : W3;
        const float* a = (which == 0) ? a1s : (which == 1) ? a1d : (which == 2) ? a3s : a3d;
        float s = 0.f;
        for (int co = 0; co < 128; ++co) s += W[ci * 128 + co] * a[co];
        wa[t] = s;
    }
}

// ---------------- GEMV: as_[n] = x[n,:].was, ad_[n] = x[n,:].wad ----------------

__global__ __launch_bounds__(256) void gemv_k(const float* __restrict__ X, const float* __restrict__ was,
                                              const float* __restrict__ wad, float* __restrict__ as_,
                                              float* __restrict__ ad_, int N) {
    int wid  = (blockIdx.x * 256 + threadIdx.x) >> 6;
    int lane = threadIdx.x & 63;
    if (wid >= N) return;
    float xv = X[(size_t)wid * 64 + lane];
    float s1 = xv * was[lane];
    float s2 = xv * wad[lane];
    #pragma unroll
    for (int off = 32; off; off >>= 1) {
        s1 += __shfl_xor(s1, off);
        s2 += __shfl_xor(s2, off);
    }
    if (lane == 0) { as_[wid] = s1; ad_[wid] = s2; }
}

// ---------------- GEMM: H = X @ W, fp32, float4 LDS pipes ----------------
// Thread owns 4 CONTIGUOUS cols [4ct, 4ct+4) -> b128 LDS reads + dwordx4 store.

template <int CIN, int COUT, bool ATT, bool BIASACT>
__global__ __launch_bounds__(256) void gemm_k(const float* __restrict__ X, const float* __restrict__ W,
                                              const float* __restrict__ a_s, const float* __restrict__ a_d,
                                              const float* __restrict__ bias,
                                              float* __restrict__ H, float* __restrict__ as_,
                                              float* __restrict__ ad_, int N) {
    constexpr int RB  = (CIN == 128 && COUT == 64) ? 32 : 64;
    constexpr int NCT = COUT / 4;
    constexpr int NRT = 256 / NCT;
    constexpr int RT  = RB / NRT;
    constexpr int XP  = CIN + 4;  // pad: row stride != 0 mod 32 dwords
    __shared__ float Xs[RB][XP];
    __shared__ float Ws[CIN][COUT];
    int tid  = threadIdx.x;
    int row0 = blockIdx.x * RB;

    for (int i = tid; i < CIN * COUT / 4; i += 256)
        *(float4*)&((float*)Ws)[i * 4] = *(const float4*)&W[i * 4];
    for (int i = tid; i < RB * CIN / 4; i += 256) {
        int r = i / (CIN / 4), k4 = i % (CIN / 4);
        int gr = row0 + r;
        float4 v = {0.f, 0.f, 0.f, 0.f};
        if (gr < N) v = *(const float4*)&X[(size_t)gr * CIN + k4 * 4];
        *(float4*)&Xs[r][k4 * 4] = v;
    }
    __syncthreads();

    int ct = tid % NCT;
    int rt = tid / NCT;
    float acc[RT][4] = {};
    for (int k = 0; k < CIN; k += 4) {
        float4 w0 = *(float4*)&Ws[k][ct * 4];
        float4 w1 = *(float4*)&Ws[k + 1][ct * 4];
        float4 w2 = *(float4*)&Ws[k + 2][ct * 4];
        float4 w3 = *(float4*)&Ws[k + 3][ct * 4];
        #pragma unroll
        for (int i = 0; i < RT; ++i) {
            float4 xv = *(float4*)&Xs[rt + i * NRT][k];
            acc[i][0] += xv.x * w0.x + xv.y * w1.x + xv.z * w2.x + xv.w * w3.x;
            acc[i][1] += xv.x * w0.y + xv.y * w1.y + xv.z * w2.y + xv.w * w3.y;
            acc[i][2] += xv.x * w0.z + xv.y * w1.z + xv.z * w2.z + xv.w * w3.z;
            acc[i][3] += xv.x * w0.w + xv.y * w1.w + xv.z * w2.w + xv.w * w3.w;
        }
    }

    float asv[4], adv[4], bv[4];
    #pragma unroll
    for (int j = 0; j < 4; ++j) {
        if (ATT) { asv[j] = a_s[ct * 4 + j]; adv[j] = a_d[ct * 4 + j]; }
        if (BIASACT) bv[j] = bias[ct * 4 + j];
    }

    #pragma unroll
    for (int i = 0; i < RT; ++i) {
        int gr = row0 + rt + i * NRT;
        if (BIASACT) {
            #pragma unroll
            for (int j = 0; j < 4; ++j) {
                float v = acc[i][j] + bv[j];
                acc[i][j] = v > 0.f ? v : 0.01f * v;
            }
        }
        float s1 = 0.f, s2 = 0.f;
        if (ATT) {
            s1 = acc[i][0] * asv[0] + acc[i][1] * asv[1] + acc[i][2] * asv[2] + acc[i][3] * asv[3];
            s2 = acc[i][0] * adv[0] + acc[i][1] * adv[1] + acc[i][2] * adv[2] + acc[i][3] * adv[3];
            #pragma unroll
            for (int off = 1; off < NCT; off <<= 1) {
                s1 += __shfl_xor(s1, off);
                s2 += __shfl_xor(s2, off);
            }
        }
        if (gr < N) {
            float4 o = {acc[i][0], acc[i][1], acc[i][2], acc[i][3]};
            *(float4*)&H[(size_t)gr * COUT + ct * 4] = o;
            if (ATT && ct == 0) { as_[gr] = s1; ad_[gr] = s2; }
        }
    }
}

// ---------------- aggregate ----------------
// (s,w) staged in LDS once per 64-edge chunk; inner loop broadcasts via
// ds_read_b64 (uniform addr) instead of v_readlane. Tails graded 16/8/4.
// MODE 0: plain weighted mean (C=64)
// MODE 1: +bias +leaky(0.01) +fused GEMV for next layer's logits (C=64)
// MODE 2: +bias, C=32 (final output; 2 edges per gather slot)

template <int C, int MODE>
__global__ __launch_bounds__(256) void agg_k(const float* __restrict__ H, const float* __restrict__ as_,
                                             const float* __restrict__ ad_, const int* __restrict__ rowp,
                                             const int* __restrict__ col, const float* __restrict__ bias,
                                             const float* __restrict__ was, const float* __restrict__ wad,
                                             float* __restrict__ out, float* __restrict__ oas,
                                             float* __restrict__ oad, int N) {
    __shared__ int2 sw[4][64];
    int wid  = (blockIdx.x * 256 + threadIdx.x) >> 6;
    int lane = threadIdx.x & 63;
    int wvi  = threadIdx.x >> 6;
    if (wid >= N) return;
    float adi = ad_[wid];
    int beg = rowp[wid], end = rowp[wid + 1];
    float denom = 0.f;
    float a0 = 0.f, a1 = 0.f, a2 = 0.f, a3 = 0.f;
    const int sub = lane >> 5;
    const int c32 = lane & 31;

    auto g16 = [&](int j) {
        float hv[16], wv[16];
        #pragma unroll
        for (int u = 0; u < 16; ++u) {
            int2 p = sw[wvi][j + u];
            wv[u] = __int_as_float(p.y);
            hv[u] = H[(p.x << 6) | lane];
        }
        #pragma unroll
        for (int u = 0; u < 16; u += 4) {
            a0 += wv[u] * hv[u]; a1 += wv[u + 1] * hv[u + 1];
            a2 += wv[u + 2] * hv[u + 2]; a3 += wv[u + 3] * hv[u + 3];
        }
    };
    auto g8 = [&](int j) {
        float hv[8], wv[8];
        #pragma unroll
        for (int u = 0; u < 8; ++u) {
            int2 p = sw[wvi][j + u];
            wv[u] = __int_as_float(p.y);
            hv[u] = H[(p.x << 6) | lane];
        }
        #pragma unroll
        for (int u = 0; u < 8; u += 4) {
            a0 += wv[u] * hv[u]; a1 += wv[u + 1] * hv[u + 1];
            a2 += wv[u + 2] * hv[u + 2]; a3 += wv[u + 3] * hv[u + 3];
        }
    };
    auto g4 = [&](int j) {
        float hv[4], wv[4];
        #pragma unroll
        for (int u = 0; u < 4; ++u) {
            int2 p = sw[wvi][j + u];
            wv[u] = __int_as_float(p.y);
            hv[u] = H[(p.x << 6) | lane];
        }
        a0 += wv[0] * hv[0]; a1 += wv[1] * hv[1];
        a2 += wv[2] * hv[2]; a3 += wv[3] * hv[3];
    };
    auto g16_32 = [&](int j) {  // 16 edges, 8 slots/lane-half
        float hv[8], wv[8];
        #pragma unroll
        for (int u = 0; u < 8; ++u) {
            int2 p = sw[wvi][j + 2 * u + sub];
            wv[u] = __int_as_float(p.y);
            hv[u] = H[(p.x << 5) | c32];
        }
        #pragma unroll
        for (int u = 0; u < 8; u += 4) {
            a0 += wv[u] * hv[u]; a1 += wv[u + 1] * hv[u + 1];
            a2 += wv[u + 2] * hv[u + 2]; a3 += wv[u + 3] * hv[u + 3];
        }
    };
    auto g8_32 = [&](int j) {  // 8 edges, 4 slots
        float hv[4], wv[4];
        #pragma unroll
        for (int u = 0; u < 4; ++u) {
            int2 p = sw[wvi][j + 2 * u + sub];
            wv[u] = __int_as_float(p.y);
            hv[u] = H[(p.x << 5) | c32];
        }
        a0 += wv[0] * hv[0]; a1 += wv[1] * hv[1];
        a2 += wv[2] * hv[2]; a3 += wv[3] * hv[3];
    };

    for (int base = beg; base < end; base += 64) {
        int cnt = end - base;
        if (cnt > 64) cnt = 64;
        int s_l = 0; float w_l = 0.f;
        if (lane < cnt) {
            s_l = col[base + lane];
            float e = as_[s_l] + adi;
            e = e > 0.f ? e : NEG_ATT * e;
            w_l = __expf(e);
        }
        denom += w_l;
        sw[wvi][lane] = make_int2(s_l, __float_as_int(w_l));

        int j = 0;
        if (C == 64) {
            for (; j + 16 <= cnt; j += 16) g16(j);
            int rem = cnt - j;
            if (rem > 8) g16(j);
            else if (rem > 4) g8(j);
            else if (rem > 0) g4(j);
        } else {
            for (; j + 16 <= cnt; j += 16) g16_32(j);
            int rem = cnt - j;
            if (rem > 8) g16_32(j);
            else if (rem > 0) g8_32(j);
        }
    }

    float acc = (a0 + a1) + (a2 + a3);
    #pragma unroll
    for (int off = 32; off; off >>= 1) denom += __shfl_xor(denom, off);
    if (C == 32) acc += __shfl_xor(acc, 32);  // fold the two edge-halves

    float inv = 1.f / denom;
    float v = acc * inv;
    if (MODE == 1) {
        v += bias[lane];
        v = v > 0.f ? v : 0.01f * v;
        out[((size_t)wid << 6) | lane] = v;
        float s1 = v * was[lane];
        float s2 = v * wad[lane];
        #pragma unroll
        for (int off = 32; off; off >>= 1) {
            s1 += __shfl_xor(s1, off);
            s2 += __shfl_xor(s2, off);
        }
        if (lane == 0) { oas[wid] = s1; oad[wid] = s2; }
    } else if (MODE == 2) {
        if (lane < 32) out[((size_t)wid << 5) | c32] = v + bias[c32];
    } else {
        out[((size_t)wid << 6) | lane] = v;
    }
}

// ---------------- launch ----------------

extern "C" void kernel_launch(void* const* d_in, const int* in_sizes, int n_in,
                              void* d_out, int out_size, void* d_ws, size_t ws_size,
                              hipStream_t stream) {
    const float* x  = (const float*)d_in[0];
    const int* ei   = (const int*)d_in[1];
    const float* W1 = (const float*)d_in[2];
    const float* a1s = (const float*)d_in[3];
    const float* a1d = (const float*)d_in[4];
    const float* b1  = (const float*)d_in[5];
    const float* W2 = (const float*)d_in[6];
    const float* a2s = (const float*)d_in[7];
    const float* a2d = (const float*)d_in[8];
    const float* b2  = (const float*)d_in[9];
    const float* W3 = (const float*)d_in[10];
    const float* a3s = (const float*)d_in[11];
    const float* a3d = (const float*)d_in[12];
    const float* b3  = (const float*)d_in[13];
    const float* W4 = (const float*)d_in[14];
    const float* a4s = (const float*)d_in[15];
    const float* a4d = (const float*)d_in[16];
    const float* b4  = (const float*)d_in[17];

    const int N = in_sizes[0] / 64;     // 50000
    const int E = in_sizes[1] / 2;      // 800000
    const int ET = E + N;
    const int* src = ei;
    const int* dst = ei + E;

    // workspace layout
    float* bufA = (float*)d_ws;             // N*128
    float* bufB = bufA + (size_t)N * 128;   // N*128
    float* asA  = bufB + (size_t)N * 128;   // N
    float* adA  = asA + N;                  // N
    float* asB  = adA + N;                  // N
    float* adB  = asB + N;                  // N
    float* wa   = adB + N;                  // 256 (4x64)
    int* cnt    = (int*)(wa + 256);         // N
    int* rowp   = cnt + N;                  // N+1
    int* col    = rowp + N + 1;             // ET
    int* bsum   = col + ET;                 // <=256

    const int NB = (N + 255) / 256;
    const int STEP = (N + 7) / 8;           // dst-range per XCD partition

    // ---- setup: zero cnt + wa vectors ----
    setup_k<<<NB + 1, 256, 0, stream>>>(cnt, N, NB, W1, a1s, a1d, W3, a3s, a3d, wa);
    float* wa1s = wa, *wa1d = wa + 64, *wa3s = wa + 128, *wa3d = wa + 192;

    // ---- CSR build (dst-sorted), XCD-partitioned count/scatter ----
    count_k<<<((E + 255) / 256) * 8, 256, 0, stream>>>(dst, cnt, E, STEP);
    scan_block_k<<<NB, 256, 0, stream>>>(cnt, rowp, bsum, N);
    scan_bsum_k<<<1, 256, 0, stream>>>(bsum, NB);
    add_off_k<<<NB, 256, 0, stream>>>(rowp, bsum, cnt, N);
    scatter_k<<<((ET + 255) / 256) * 8, 256, 0, stream>>>(src, dst, rowp, cnt, col, E, N, STEP);

    const int NWAVE = (N * 64 + 255) / 256;

    // ---- layer 1 (aggregate-first): T1 = Ahat1 @ x ; H1 = leaky(T1 @ W1 + b1) ----
    gemv_k<<<NWAVE, 256, 0, stream>>>(x, wa1s, wa1d, asA, adA, N);
    agg_k<64, 0><<<NWAVE, 256, 0, stream>>>(x, asA, adA, rowp, col, nullptr, nullptr, nullptr,
                                            bufA, nullptr, nullptr, N);
    gemm_k<64, 128, false, true><<<(N + 63) / 64, 256, 0, stream>>>(bufA, W1, nullptr, nullptr, b1,
                                                                    bufB, nullptr, nullptr, N);

    // ---- layer 2 (standard) ----
    gemm_k<128, 64, true, false><<<(N + 31) / 32, 256, 0, stream>>>(bufB, W2, a2s, a2d, nullptr,
                                                                    bufA, asB, adB, N);
    agg_k<64, 1><<<NWAVE, 256, 0, stream>>>(bufA, asB, adB, rowp, col, b2, wa3s, wa3d,
                                            bufB, asA, adA, N);

    // ---- layer 3 (aggregate-first) ----
    agg_k<64, 0><<<NWAVE, 256, 0, stream>>>(bufB, asA, adA, rowp, col, nullptr, nullptr, nullptr,
                                            bufA, nullptr, nullptr, N);
    gemm_k<64, 128, false, true><<<(N + 63) / 64, 256, 0, stream>>>(bufA, W3, nullptr, nullptr, b3,
                                                                    bufB, nullptr, nullptr, N);

    // ---- layer 4 (standard) ----
    gemm_k<128, 32, true, false><<<(N + 63) / 64, 256, 0, stream>>>(bufB, W4, a4s, a4d, nullptr,
                                                                    bufA, asB, adB, N);
    agg_k<32, 2><<<NWAVE, 256, 0, stream>>>(bufA, asB, adB, rowp, col, b4, nullptr, nullptr,
                                            (float*)d_out, nullptr, nullptr, N);
}